// Round 20
// baseline (215.920 us; speedup 1.0000x reference)
//
#include <hip/hip_runtime.h>
#include <hip/hip_bf16.h>

#define HDIM 4096
#define EDIM 64
#define ITOK 4          // tokens per wave
#define NW   8          // waves per block (512 threads)
#define BH   64         // h-chunk staged in LDS
#define NCH  (HDIM/BH)  // 64 chunks

typedef float f32x4 __attribute__((ext_vector_type(4)));
typedef float f32x2 __attribute__((ext_vector_type(2)));

// Semantics (locked r16): inputs f32-backed bf16; logit = np-einsum-SSE
// 4-chain f32 mul/add (NO FMA), groups of 8 ascending h, (l0+l1)+(l2+l3),
// bf16-round, f32 routing, f32 out [idx 4T | w 4T | k T].
// r19: packed-f32 inner loop (v_pk_mul/v_pk_add, 2 chains per register pair)
// — per-chain op order and rounding bit-identical; VALU instr count halved.
__global__ __launch_bounds__(512) void router_pk(
    const float* __restrict__ hidden,
    const float* __restrict__ weight,
    float* __restrict__ out,
    int T)
{
#pragma clang fp contract(off)
    __shared__ float wlds[2][EDIM][BH + 1];   // 2 x 16.25 KB, stride 65

    const int tid  = threadIdx.x;
    const int lane = tid & 63;
    const int wv   = __builtin_amdgcn_readfirstlane(tid >> 6);
    const int t0   = (blockIdx.x * NW + wv) * ITOK;

    const int srow = tid >> 3;
    const int sq   = (tid & 7) * 8;

    f32x2 l01[ITOK], l23[ITOK];
#pragma unroll
    for (int i = 0; i < ITOK; ++i) {
        l01[i] = (f32x2){0.f, 0.f};
        l23[i] = (f32x2){0.f, 0.f};
    }

    // ---- prologue: stage chunk 0 ----
    {
        const float* wp = weight + (size_t)srow * HDIM + sq;
        f32x4 v0 = *reinterpret_cast<const f32x4*>(wp);
        f32x4 v1 = *reinterpret_cast<const f32x4*>(wp + 4);
        wlds[0][srow][sq + 0] = v0.x; wlds[0][srow][sq + 1] = v0.y;
        wlds[0][srow][sq + 2] = v0.z; wlds[0][srow][sq + 3] = v0.w;
        wlds[0][srow][sq + 4] = v1.x; wlds[0][srow][sq + 5] = v1.y;
        wlds[0][srow][sq + 6] = v1.z; wlds[0][srow][sq + 7] = v1.w;
    }
    __syncthreads();

    for (int c = 0; c < NCH; ++c) {
        const int cur = c & 1;
        if (c + 1 < NCH) {
            const float* wp = weight + (size_t)srow * HDIM + (c + 1) * BH + sq;
            f32x4 v0 = *reinterpret_cast<const f32x4*>(wp);
            f32x4 v1 = *reinterpret_cast<const f32x4*>(wp + 4);
            wlds[cur ^ 1][srow][sq + 0] = v0.x; wlds[cur ^ 1][srow][sq + 1] = v0.y;
            wlds[cur ^ 1][srow][sq + 2] = v0.z; wlds[cur ^ 1][srow][sq + 3] = v0.w;
            wlds[cur ^ 1][srow][sq + 4] = v1.x; wlds[cur ^ 1][srow][sq + 5] = v1.y;
            wlds[cur ^ 1][srow][sq + 6] = v1.z; wlds[cur ^ 1][srow][sq + 7] = v1.w;
        }

        const int h0 = c * BH;
#pragma unroll
        for (int g = 0; g < BH / 8; ++g) {
            const f32x4 wa = *reinterpret_cast<const f32x4*>(&wlds[cur][lane][g * 8]);
            const f32x4 wb = *reinterpret_cast<const f32x4*>(&wlds[cur][lane][g * 8 + 4]);
            const f32x2 wa01 = wa.xy, wa23 = wa.zw;
            const f32x2 wb01 = wb.xy, wb23 = wb.zw;
#pragma unroll
            for (int i = 0; i < ITOK; ++i) {
                const float* hp = hidden + (size_t)(t0 + i) * HDIM + h0 + g * 8;
                const f32x4 a0 = *reinterpret_cast<const f32x4*>(hp);
                const f32x4 a1 = *reinterpret_cast<const f32x4*>(hp + 4);
                // chains 0,1 (slots x,y) then 2,3 (slots z,w); group order c then c+4
                l01[i] = l01[i] + a0.xy * wa01;   // pk_mul + pk_add, RN each elem
                l23[i] = l23[i] + a0.zw * wa23;
                l01[i] = l01[i] + a1.xy * wb01;
                l23[i] = l23[i] + a1.zw * wb23;
            }
        }
        __syncthreads();
    }

    const size_t T4 = (size_t)T * 4;

#pragma unroll 1
    for (int i = 0; i < ITOK; ++i) {
        // SSE combine: (l0+l1)+(l2+l3), exact scalar RN adds
        const float acc = __fadd_rn(__fadd_rn(l01[i].x, l01[i].y),
                                    __fadd_rn(l23[i].x, l23[i].y));
        const float lv = __bfloat162float(__float2bfloat16(acc));

        float mx = lv;
#pragma unroll
        for (int d = 1; d < 64; d <<= 1) mx = fmaxf(mx, __shfl_xor(mx, d));
        const float ev = expf(lv - mx);
        float s = ev;
#pragma unroll
        for (int d = 1; d < 64; d <<= 1) s += __shfl_xor(s, d);
        const float p = ev / s;

        float ent = p * logf(p + 1e-9f);
#pragma unroll
        for (int d = 1; d < 64; d <<= 1) ent += __shfl_xor(ent, d);
        const float Hent = -ent;

        float pv[4]; int pi[4];
        float cand = p;
#pragma unroll
        for (int r = 0; r < 4; ++r) {
            float bv = cand; int bi = lane;
#pragma unroll
            for (int d = 1; d < 64; d <<= 1) {
                float ov = __shfl_xor(bv, d);
                int   oi = __shfl_xor(bi, d);
                if (ov > bv || (ov == bv && oi < bi)) { bv = ov; bi = oi; }
            }
            pv[r] = bv; pi[r] = bi;
            if (lane == bi) cand = -1.f;
        }

        const int kk = (Hent < 0.3f) ? 1 : (Hent > 1.5f) ? 4 : 2;

        float wsum = 0.f;
#pragma unroll
        for (int r = 0; r < 4; ++r) if (r < kk) wsum += pv[r];

        if (lane == 0) {
            const size_t tt = (size_t)(t0 + i);
#pragma unroll
            for (int r = 0; r < 4; ++r) {
                out[tt * 4 + r]      = (r < kk) ? (float)pi[r] : -1.f;
                out[T4 + tt * 4 + r] = (r < kk) ? pv[r] / wsum : 0.f;
            }
            out[2 * T4 + tt] = (float)kk;
        }
    }
}

extern "C" void kernel_launch(void* const* d_in, const int* in_sizes, int n_in,
                              void* d_out, int out_size, void* d_ws, size_t ws_size,
                              hipStream_t stream) {
    const float* hidden = (const float*)d_in[0];
    const float* weight = (const float*)d_in[1];
    float* out = (float*)d_out;
    const int T = in_sizes[0] / HDIM;              // 16384
    const int blocks = T / (NW * ITOK);            // 512
    hipLaunchKernelGGL(router_pk, dim3(blocks), dim3(512), 0, stream,
                       hidden, weight, out, T);
}